// Round 1
// baseline (474.788 us; speedup 1.0000x reference)
//
#include <hip/hip_runtime.h>

typedef unsigned short ushort_t;
using floatx4 = __attribute__((__ext_vector_type__(4))) float;
using bf16x8  = __attribute__((__ext_vector_type__(8))) __bf16;

__device__ __forceinline__ ushort_t f2bf(float f) {
  unsigned int u = __builtin_bit_cast(unsigned int, f);
  u += 0x7FFFu + ((u >> 16) & 1u);   // RNE
  return (ushort_t)(u >> 16);
}
__device__ __forceinline__ float b2f(ushort_t h) {
  unsigned int u = ((unsigned int)h) << 16;
  return __builtin_bit_cast(float, u);
}

// ---------------- cast fp32 -> bf16 ----------------
__global__ void cast_f2b(const float* __restrict__ in, ushort_t* __restrict__ out, int n) {
  int i = (blockIdx.x * blockDim.x + threadIdx.x) * 4;
  if (i < n) {
    float4 v = *reinterpret_cast<const float4*>(&in[i]);
    ushort_t o0 = f2bf(v.x), o1 = f2bf(v.y), o2 = f2bf(v.z), o3 = f2bf(v.w);
    ushort4 o = make_ushort4(o0, o1, o2, o3);
    *reinterpret_cast<ushort4*>(&out[i]) = o;
  }
}

// ---------------- GEMM: C[M,N] = A[M,K] * B[N,K]^T (+bias) ----------------
// A, B bf16 row-major (K contiguous). 128x128 tile, BK=32, 4 waves of 64x64.
template<bool BF16OUT>
__global__ __launch_bounds__(256)
void gemm_bt(const ushort_t* __restrict__ A, const ushort_t* __restrict__ B,
             void* __restrict__ Cout, const float* __restrict__ bias,
             int M, int N, int K) {
  __shared__ ushort_t sA[128][40];   // +8 bf16 pad (16B), rows stay 16B aligned
  __shared__ ushort_t sB[128][40];
  const int m0 = blockIdx.y * 128, n0 = blockIdx.x * 128;
  const int tid = threadIdx.x;
  const int lane = tid & 63, w = tid >> 6;
  const int wm = (w >> 1) * 64, wn = (w & 1) * 64;
  const int grp = lane >> 4, l16 = lane & 15;
  floatx4 acc[4][4] = {};
  const int r = tid >> 2, c = (tid & 3) * 8;   // 64 rows x 4 threads x 8 elems
  const ushort_t* Ap = &A[(size_t)(m0 + r) * K + c];
  const ushort_t* Bp = &B[(size_t)(n0 + r) * K + c];
  for (int k0 = 0; k0 < K; k0 += 32) {
    *reinterpret_cast<uint4*>(&sA[r][c])      = *reinterpret_cast<const uint4*>(Ap + k0);
    *reinterpret_cast<uint4*>(&sA[r + 64][c]) = *reinterpret_cast<const uint4*>(Ap + (size_t)64 * K + k0);
    *reinterpret_cast<uint4*>(&sB[r][c])      = *reinterpret_cast<const uint4*>(Bp + k0);
    *reinterpret_cast<uint4*>(&sB[r + 64][c]) = *reinterpret_cast<const uint4*>(Bp + (size_t)64 * K + k0);
    __syncthreads();
    bf16x8 af[4], bfr[4];
#pragma unroll
    for (int i = 0; i < 4; i++)
      af[i] = *reinterpret_cast<const bf16x8*>(&sA[wm + i * 16 + l16][grp * 8]);
#pragma unroll
    for (int i = 0; i < 4; i++)
      bfr[i] = *reinterpret_cast<const bf16x8*>(&sB[wn + i * 16 + l16][grp * 8]);
#pragma unroll
    for (int i = 0; i < 4; i++)
#pragma unroll
      for (int j = 0; j < 4; j++)
        acc[i][j] = __builtin_amdgcn_mfma_f32_16x16x32_bf16(af[i], bfr[j], acc[i][j], 0, 0, 0);
    __syncthreads();
  }
  // C/D layout (m89/m91 verified): row = grp*4 + reg, col = l16
#pragma unroll
  for (int i = 0; i < 4; i++) {
    const int mb = m0 + wm + i * 16 + grp * 4;
#pragma unroll
    for (int j = 0; j < 4; j++) {
      const int nc = n0 + wn + j * 16 + l16;
      const float bv = bias ? bias[nc] : 0.0f;
#pragma unroll
      for (int rr = 0; rr < 4; rr++) {
        if (BF16OUT)
          ((ushort_t*)Cout)[(size_t)(mb + rr) * N + nc] = f2bf(acc[i][j][rr] + bv);
        else
          ((float*)Cout)[(size_t)(mb + rr) * N + nc] = acc[i][j][rr] + bv;
      }
    }
  }
}

// ---------------- QKV postprocess: RMSNorm(q,k) + rotary, layout for attention ----------------
// one wave per (bh, n) row of D=64. qkv bf16 [B*N][3072].
__global__ __launch_bounds__(256)
void qkv_post(const ushort_t* __restrict__ qkv, const float* __restrict__ pos,
              const float* __restrict__ qw, const float* __restrict__ kw,
              ushort_t* __restrict__ qr, ushort_t* __restrict__ kr, ushort_t* __restrict__ vt) {
  int wid  = blockIdx.x * 4 + (threadIdx.x >> 6);   // [0, 32*2048)
  int lane = threadIdx.x & 63;
  int bh = wid >> 11;          // b*16 + h
  int n  = wid & 2047;
  int b = bh >> 4, h = bh & 15;
  size_t row = (size_t)(b * 2048 + n) * 3072 + h * 64;
  float q = b2f(qkv[row + lane]);
  float k = b2f(qkv[row + 1024 + lane]);
  float v = b2f(qkv[row + 2048 + lane]);
  float sq = q * q, sk = k * k;
#pragma unroll
  for (int off = 32; off > 0; off >>= 1) {
    sq += __shfl_xor(sq, off);
    sk += __shfl_xor(sk, off);
  }
  q = q * rsqrtf(sq * (1.0f / 64.0f) + 1e-6f) * qw[lane];
  k = k * rsqrtf(sk * (1.0f / 64.0f) + 1e-6f) * kw[lane];
  // rotary: pairs (2i, 2i+1); even lane = real, odd = imag
  float ang = pos[n * 32 + (lane >> 1)];
  float cc = __cosf(ang), ss = __sinf(ang);
  float qp = __shfl_xor(q, 1);
  float kp = __shfl_xor(k, 1);
  float sgn = (lane & 1) ? ss : -ss;
  float qo = q * cc + qp * sgn;
  float ko = k * cc + kp * sgn;
  size_t o = (size_t)wid * 64 + lane;              // [bh][n][d]
  qr[o] = f2bf(qo);
  kr[o] = f2bf(ko);
  vt[(size_t)(bh * 64 + lane) * 2048 + n] = f2bf(v);   // v transposed: [bh][d][n]
}

// ---------------- Flash attention: per (bh, 64-row Q tile) ----------------
__global__ __launch_bounds__(256)
void flash_attn(const ushort_t* __restrict__ qr, const ushort_t* __restrict__ kr,
                const ushort_t* __restrict__ vt, ushort_t* __restrict__ aout) {
  int bh = blockIdx.y;
  int q0 = blockIdx.x * 64;
  int lane = threadIdx.x & 63, w = threadIdx.x >> 6;
  int grp = lane >> 4, l16 = lane & 15;
  __shared__ ushort_t sP[4][16][72];   // per-wave P tile, 144B rows (16B aligned)
  const size_t hb = (size_t)bh * 2048 * 64;
  const int qrow = q0 + w * 16 + l16;
  bf16x8 qa0 = *reinterpret_cast<const bf16x8*>(&qr[hb + (size_t)qrow * 64 + grp * 8]);
  bf16x8 qa1 = *reinterpret_cast<const bf16x8*>(&qr[hb + (size_t)qrow * 64 + 32 + grp * 8]);
  floatx4 o[4] = {};
  float mrow[4] = {-1e30f, -1e30f, -1e30f, -1e30f};
  float lrow[4] = {0.f, 0.f, 0.f, 0.f};
  const float scale = 0.125f;   // 64^-0.5
  for (int k0 = 0; k0 < 2048; k0 += 64) {
    // S = Q K^T  (per wave: 16q x 64k)
    floatx4 s4[4];
#pragma unroll
    for (int nt = 0; nt < 4; nt++) {
      floatx4 acc = {};
      const ushort_t* kp0 = &kr[hb + (size_t)(k0 + nt * 16 + l16) * 64 + grp * 8];
      acc = __builtin_amdgcn_mfma_f32_16x16x32_bf16(qa0, *reinterpret_cast<const bf16x8*>(kp0), acc, 0, 0, 0);
      acc = __builtin_amdgcn_mfma_f32_16x16x32_bf16(qa1, *reinterpret_cast<const bf16x8*>(kp0 + 32), acc, 0, 0, 0);
      s4[nt] = acc;
    }
    // online softmax per q-row (row r lives in 16-lane group, reg r)
    float p[4][4];
#pragma unroll
    for (int r = 0; r < 4; r++) {
      float mx = fmaxf(fmaxf(s4[0][r], s4[1][r]), fmaxf(s4[2][r], s4[3][r])) * scale;
      mx = fmaxf(mx, __shfl_xor(mx, 1));
      mx = fmaxf(mx, __shfl_xor(mx, 2));
      mx = fmaxf(mx, __shfl_xor(mx, 4));
      mx = fmaxf(mx, __shfl_xor(mx, 8));
      float mnew = fmaxf(mrow[r], mx);
      float alpha = __expf(mrow[r] - mnew);
      float rs = 0.f;
#pragma unroll
      for (int nt = 0; nt < 4; nt++) {
        float pv = __expf(s4[nt][r] * scale - mnew);
        p[nt][r] = pv;
        rs += pv;
      }
      rs += __shfl_xor(rs, 1);
      rs += __shfl_xor(rs, 2);
      rs += __shfl_xor(rs, 4);
      rs += __shfl_xor(rs, 8);
      lrow[r] = lrow[r] * alpha + rs;
      mrow[r] = mnew;
#pragma unroll
      for (int dt = 0; dt < 4; dt++) o[dt][r] *= alpha;
    }
    // P: C-layout -> LDS -> A-layout (bf16)
#pragma unroll
    for (int nt = 0; nt < 4; nt++)
#pragma unroll
      for (int r = 0; r < 4; r++)
        sP[w][grp * 4 + r][nt * 16 + l16] = f2bf(p[nt][r]);
    __syncthreads();
    bf16x8 pa0 = *reinterpret_cast<const bf16x8*>(&sP[w][l16][grp * 8]);
    bf16x8 pa1 = *reinterpret_cast<const bf16x8*>(&sP[w][l16][32 + grp * 8]);
#pragma unroll
    for (int dt = 0; dt < 4; dt++) {
      const ushort_t* vp = &vt[(size_t)(bh * 64 + dt * 16 + l16) * 2048 + k0 + grp * 8];
      o[dt] = __builtin_amdgcn_mfma_f32_16x16x32_bf16(pa0, *reinterpret_cast<const bf16x8*>(vp), o[dt], 0, 0, 0);
      o[dt] = __builtin_amdgcn_mfma_f32_16x16x32_bf16(pa1, *reinterpret_cast<const bf16x8*>(vp + 32), o[dt], 0, 0, 0);
    }
    __syncthreads();
  }
  // epilogue: O /= l, write bf16 [b*2048+n][h*64+d]
  int b = bh >> 4, h = bh & 15;
#pragma unroll
  for (int dt = 0; dt < 4; dt++) {
#pragma unroll
    for (int r = 0; r < 4; r++) {
      int qq = q0 + w * 16 + grp * 4 + r;
      size_t off = (size_t)(b * 2048 + qq) * 1024 + h * 64 + dt * 16 + l16;
      aout[off] = f2bf(o[dt][r] / lrow[r]);
    }
  }
}

extern "C" void kernel_launch(void* const* d_in, const int* in_sizes, int n_in,
                              void* d_out, int out_size, void* d_ws, size_t ws_size,
                              hipStream_t stream) {
  const float* x      = (const float*)d_in[0];   // [2,2048,1024]
  const float* pos    = (const float*)d_in[1];   // [2048,32]
  const float* qkv_w  = (const float*)d_in[2];   // [3072,1024]
  const float* q_nw   = (const float*)d_in[3];   // [64]
  const float* k_nw   = (const float*)d_in[4];   // [64]
  const float* proj_w = (const float*)d_in[5];   // [1024,1024]
  const float* proj_b = (const float*)d_in[6];   // [1024]
  float* out = (float*)d_out;                    // [2,2048,1024] fp32

  // workspace layout (all bf16 = ushort), total 72 MB
  ushort_t* x_b     = (ushort_t*)d_ws;                         // 4096*1024
  ushort_t* qkvw_b  = x_b     + (size_t)4096 * 1024;           // 3072*1024
  ushort_t* projw_b = qkvw_b  + (size_t)3072 * 1024;           // 1024*1024
  ushort_t* qkv_b   = projw_b + (size_t)1024 * 1024;           // 4096*3072
  ushort_t* q_r     = qkv_b   + (size_t)4096 * 3072;           // 32*2048*64
  ushort_t* k_r     = q_r     + (size_t)32 * 2048 * 64;
  ushort_t* v_t     = k_r     + (size_t)32 * 2048 * 64;
  ushort_t* a_out   = v_t     + (size_t)32 * 2048 * 64;        // 4096*1024

  cast_f2b<<<4096 * 1024 / 4 / 256, 256, 0, stream>>>(x, x_b, 4096 * 1024);
  cast_f2b<<<3072 * 1024 / 4 / 256, 256, 0, stream>>>(qkv_w, qkvw_b, 3072 * 1024);
  cast_f2b<<<1024 * 1024 / 4 / 256, 256, 0, stream>>>(proj_w, projw_b, 1024 * 1024);

  // QKV: [4096,3072] = x_b[4096,1024] @ qkv_w[3072,1024]^T   -> bf16
  gemm_bt<true><<<dim3(3072 / 128, 4096 / 128), 256, 0, stream>>>(
      x_b, qkvw_b, (void*)qkv_b, nullptr, 4096, 3072, 1024);

  // RMSNorm + rotary + relayout
  qkv_post<<<(2 * 16 * 2048) / 4, 256, 0, stream>>>(qkv_b, pos, q_nw, k_nw, q_r, k_r, v_t);

  // flash attention: grid (q-tiles, bh)
  flash_attn<<<dim3(2048 / 64, 32), 256, 0, stream>>>(q_r, k_r, v_t, a_out);

  // proj: out[4096,1024] = a_out[4096,1024] @ proj_w[1024,1024]^T + b  -> fp32
  gemm_bt<false><<<dim3(1024 / 128, 4096 / 128), 256, 0, stream>>>(
      a_out, projw_b, (void*)out, proj_b, 4096, 1024, 1024);
}